// Round 4
// baseline (1412.274 us; speedup 1.0000x reference)
//
#include <hip/hip_runtime.h>
#include <math.h>

// Problem constants (fixed by reference setup_inputs)
#define BB    8
#define CC    256      // channels
#define RR    256      // token bank size
#define HWV   16384    // H*W
#define NPIX  131072   // B*H*W
#define COUT  256
#define TILE  32       // pixels per block

typedef float f4 __attribute__((ext_vector_type(4)));

// ---------------- kM: M[o][r] = sum_c W2[o][c] * T[r][c]  (W2 = w_out[:,256:512])
//                  + zero the BN accumulators (block o zeroes gsum[o], gss[o])
__global__ void kM(const float* __restrict__ w_out, const float* __restrict__ t_items,
                   float* __restrict__ M, float* __restrict__ gsum, float* __restrict__ gss) {
    __shared__ float wl[CC];
    const int o = blockIdx.x;
    const int t = threadIdx.x;           // 256 threads, t == r
    if (t == 0) { gsum[o] = 0.0f; gss[o] = 0.0f; }
    wl[t] = w_out[o * 512 + 256 + t];
    __syncthreads();
    const f4* tr = (const f4*)(t_items + t * CC);
    float acc = 0.0f;
    #pragma unroll
    for (int c4 = 0; c4 < 64; c4++) {
        f4 v = tr[c4];
        acc = fmaf(wl[c4*4+0], v[0], acc);
        acc = fmaf(wl[c4*4+1], v[1], acc);
        acc = fmaf(wl[c4*4+2], v[2], acc);
        acc = fmaf(wl[c4*4+3], v[3], acc);
    }
    M[o * RR + t] = acc;
}

// ---------------- k1: fused normalize -> {cue, W1@qhat} -> softmax -> y += M@attn
// LDS strategy: qs and at share ONE 32KB buffer (qa). qs is dead after the merged
// c-loop (cue+yW both read it), so cue overwrites it after a barrier.
// 33.4KB LDS -> 4 blocks/CU (16 waves/CU); launch_bounds(256,4) caps VGPR at 128.
__launch_bounds__(256, 4)
__global__ void k1(const float* __restrict__ query, const float* __restrict__ t_items,
                   const float* __restrict__ w_out, const float* __restrict__ Mmat,
                   float* __restrict__ out, float* __restrict__ gsum, float* __restrict__ gss) {
    __shared__ float qa[CC][TILE];   // 32 KB — qhat tile, then cue/attn tile
    __shared__ float red[8][TILE];
    __shared__ float pscale[TILE];
    __shared__ float smax[TILE];
    __shared__ float ssumi[TILE];

    const int t    = threadIdx.x;
    const int pix0 = blockIdx.x * TILE;
    const int b    = pix0 >> 14;
    const int hw0  = pix0 & (HWV - 1);
    const int qbase = ((b * CC) << 14) + hw0;

    // ---- Stage A: load query tile (coalesced float4), compute L2 scale, normalize in LDS
    {
        const f4* qg = (const f4*)(query + qbase);
        #pragma unroll
        for (int k = 0; k < 8; k++) {
            int f  = t + k * 256;          // float4 id: 2048 total
            int c  = f >> 3;
            int p4 = f & 7;
            f4 v = qg[c * (HWV / 4) + p4];
            *((f4*)&qa[c][p4 * 4]) = v;
        }
    }
    __syncthreads();
    {
        int p = t & 31, g = t >> 5;
        float s = 0.0f;
        #pragma unroll
        for (int cc = 0; cc < 32; cc++) { float v = qa[g * 32 + cc][p]; s = fmaf(v, v, s); }
        red[g][p] = s;
        __syncthreads();
        if (t < 32) {
            float tot = 0.0f;
            #pragma unroll
            for (int g2 = 0; g2 < 8; g2++) tot += red[g2][t];
            pscale[t] = 1.0f / fmaxf(sqrtf(tot), 1e-12f);
        }
        __syncthreads();
        #pragma unroll
        for (int k = 0; k < 8; k++) {
            int f  = t + k * 256;
            int c  = f >> 3;
            int p4 = f & 7;
            f4 v = *((f4*)&qa[c][p4 * 4]);
            v[0] *= pscale[p4 * 4 + 0];
            v[1] *= pscale[p4 * 4 + 1];
            v[2] *= pscale[p4 * 4 + 2];
            v[3] *= pscale[p4 * 4 + 3];
            *((f4*)&qa[c][p4 * 4]) = v;
        }
    }
    __syncthreads();

    const int pg = t & 7;        // pixel group
    const int p0 = pg * 4;
    const int gg = t >> 3;       // 0..31: row group (r or o)
    const int r0 = gg * 8;

    // ---- Merged stage B: cue[r][p] AND yW[o][p] in one pass over qhat
    f4 accC[8] = {f4(0.f),f4(0.f),f4(0.f),f4(0.f),f4(0.f),f4(0.f),f4(0.f),f4(0.f)};
    f4 accY[8] = {f4(0.f),f4(0.f),f4(0.f),f4(0.f),f4(0.f),f4(0.f),f4(0.f),f4(0.f)};
    {
        const float* Trow = t_items + r0 * CC;
        const float* Wrow = w_out + r0 * 512;
        for (int c4 = 0; c4 < 64; c4++) {
            int c = c4 * 4;
            f4 qv0 = *((const f4*)&qa[c + 0][p0]);
            f4 qv1 = *((const f4*)&qa[c + 1][p0]);
            f4 qv2 = *((const f4*)&qa[c + 2][p0]);
            f4 qv3 = *((const f4*)&qa[c + 3][p0]);
            #pragma unroll
            for (int i = 0; i < 8; i++) {
                f4 tv = *((const f4*)(Trow + i * CC + c));
                accC[i] += tv[0] * qv0;
                accC[i] += tv[1] * qv1;
                accC[i] += tv[2] * qv2;
                accC[i] += tv[3] * qv3;
            }
            #pragma unroll
            for (int i = 0; i < 8; i++) {
                f4 wv = *((const f4*)(Wrow + i * 512 + c));
                accY[i] += wv[0] * qv0;
                accY[i] += wv[1] * qv1;
                accY[i] += wv[2] * qv2;
                accY[i] += wv[3] * qv3;
            }
        }
    }
    __syncthreads();                       // everyone done READING qa (qhat is dead)
    #pragma unroll
    for (int i = 0; i < 8; i++) *((f4*)&qa[r0 + i][p0]) = accC[i];   // cue overwrites qa
    __syncthreads();

    // ---- Softmax over r (per pixel), normalized attn left in qa[][]
    {
        int p = t & 31, g = t >> 5;
        float m = -1e30f;
        #pragma unroll
        for (int cc = 0; cc < 32; cc++) m = fmaxf(m, qa[g * 32 + cc][p]);
        red[g][p] = m;
        __syncthreads();
        if (t < 32) {
            float mm = red[0][t];
            #pragma unroll
            for (int g2 = 1; g2 < 8; g2++) mm = fmaxf(mm, red[g2][t]);
            smax[t] = mm;
        }
        __syncthreads();
        float s = 0.0f;
        #pragma unroll
        for (int cc = 0; cc < 32; cc++) {
            float e = expf(qa[g * 32 + cc][p] - smax[p]);
            qa[g * 32 + cc][p] = e;
            s += e;
        }
        red[g][p] = s;
        __syncthreads();
        if (t < 32) {
            float tot = 0.0f;
            #pragma unroll
            for (int g2 = 0; g2 < 8; g2++) tot += red[g2][t];
            ssumi[t] = 1.0f / tot;
        }
        __syncthreads();
        #pragma unroll
        for (int k = 0; k < 8; k++) {
            int f  = t + k * 256;
            int rr = f >> 3;
            int p4 = f & 7;
            f4 v = *((f4*)&qa[rr][p4 * 4]);
            v[0] *= ssumi[p4 * 4 + 0];
            v[1] *= ssumi[p4 * 4 + 1];
            v[2] *= ssumi[p4 * 4 + 2];
            v[3] *= ssumi[p4 * 4 + 3];
            *((f4*)&qa[rr][p4 * 4]) = v;
        }
    }
    __syncthreads();

    // ---- Stage C2: accY += M @ attn, then store y + BN partial sums
    {
        const int o0 = r0;
        const float* Mrow = Mmat + o0 * RR;
        for (int r4 = 0; r4 < 64; r4++) {
            int r = r4 * 4;
            f4 av0 = *((const f4*)&qa[r + 0][p0]);
            f4 av1 = *((const f4*)&qa[r + 1][p0]);
            f4 av2 = *((const f4*)&qa[r + 2][p0]);
            f4 av3 = *((const f4*)&qa[r + 3][p0]);
            #pragma unroll
            for (int i = 0; i < 8; i++) {
                f4 mv = *((const f4*)(Mrow + i * RR + r));
                accY[i] += mv[0] * av0;
                accY[i] += mv[1] * av1;
                accY[i] += mv[2] * av2;
                accY[i] += mv[3] * av3;
            }
        }
        const int obase = ((b * COUT) << 14) + hw0;
        float psum[8], psq[8];
        #pragma unroll
        for (int i = 0; i < 8; i++) {
            f4 v = accY[i];
            *((f4*)(out + obase + (o0 + i) * HWV + p0)) = v;
            psum[i] = (v[0] + v[1]) + (v[2] + v[3]);
            psq[i]  = fmaf(v[0], v[0], fmaf(v[1], v[1], fmaf(v[2], v[2], v[3] * v[3])));
        }
        #pragma unroll
        for (int off = 1; off < 8; off <<= 1) {
            #pragma unroll
            for (int i = 0; i < 8; i++) {
                psum[i] += __shfl_xor(psum[i], off);
                psq[i]  += __shfl_xor(psq[i], off);
            }
        }
        if (pg == 0) {
            #pragma unroll
            for (int i = 0; i < 8; i++) {
                atomicAdd(&gsum[o0 + i], psum[i]);
                atomicAdd(&gss[o0 + i], psq[i]);
            }
        }
    }
}

// ---------------- k2: finalize BN affine params
__global__ void k2(const float* __restrict__ gsum, const float* __restrict__ gss,
                   const float* __restrict__ gamma, const float* __restrict__ beta,
                   float* __restrict__ params) {
    const int o = threadIdx.x;   // 256
    const float inv_n = 1.0f / (float)NPIX;
    float mean = gsum[o] * inv_n;
    float var  = gss[o] * inv_n - mean * mean;
    float sc   = gamma[o] / sqrtf(var + 1e-5f);
    params[o]        = sc;
    params[256 + o]  = beta[o] - mean * sc;
}

// ---------------- k3: apply BN + ReLU in place on d_out
__global__ void k3(float* __restrict__ out, const float* __restrict__ params) {
    const int idx = blockIdx.x * 256 + threadIdx.x;      // float4 index, total 8388608
    const int o = (idx >> 12) & 255;                     // (idx*4) >> 14
    f4* o4 = (f4*)out;
    f4 v = o4[idx];
    float sc = params[o], bi = params[256 + o];
    v[0] = fmaxf(fmaf(v[0], sc, bi), 0.0f);
    v[1] = fmaxf(fmaf(v[1], sc, bi), 0.0f);
    v[2] = fmaxf(fmaf(v[2], sc, bi), 0.0f);
    v[3] = fmaxf(fmaf(v[3], sc, bi), 0.0f);
    o4[idx] = v;
}

extern "C" void kernel_launch(void* const* d_in, const int* in_sizes, int n_in,
                              void* d_out, int out_size, void* d_ws, size_t ws_size,
                              hipStream_t stream) {
    const float* query   = (const float*)d_in[0];
    const float* t_items = (const float*)d_in[1];
    const float* w_out   = (const float*)d_in[2];
    const float* gamma   = (const float*)d_in[3];
    const float* beta    = (const float*)d_in[4];
    float* out = (float*)d_out;
    float* ws  = (float*)d_ws;

    // ws layout (floats): M[65536] | gsum[256] | gss[256] | params[512]
    float* Mmat   = ws;
    float* gsum   = ws + 65536;
    float* gss    = ws + 65536 + 256;
    float* params = ws + 65536 + 512;

    kM<<<256, 256, 0, stream>>>(w_out, t_items, Mmat, gsum, gss);
    k1<<<NPIX / TILE, 256, 0, stream>>>(query, t_items, w_out, Mmat, out, gsum, gss);
    k2<<<1, 256, 0, stream>>>(gsum, gss, gamma, beta, params);
    k3<<<NPIX * COUT / 4 / 256, 256, 0, stream>>>(out, params);
}

// Round 5
// 1411.583 us; speedup vs baseline: 1.0005x; 1.0005x over previous
//
#include <hip/hip_runtime.h>
#include <math.h>

// Problem constants (fixed by reference setup_inputs)
#define BB    8
#define CC    256      // channels
#define RR    256      // token bank size
#define HWV   16384    // H*W
#define NPIX  131072   // B*H*W
#define COUT  256
#define TILE  32       // pixels per block

typedef float f4 __attribute__((ext_vector_type(4)));

// ---------------- kM: M[o][r] = sum_c W2[o][c] * T[r][c]  (W2 = w_out[:,256:512])
//                  + zero the BN accumulators (block o zeroes gsum[o], gss[o])
__global__ void kM(const float* __restrict__ w_out, const float* __restrict__ t_items,
                   float* __restrict__ M, float* __restrict__ gsum, float* __restrict__ gss) {
    __shared__ float wl[CC];
    const int o = blockIdx.x;
    const int t = threadIdx.x;           // 256 threads, t == r
    if (t == 0) { gsum[o] = 0.0f; gss[o] = 0.0f; }
    wl[t] = w_out[o * 512 + 256 + t];
    __syncthreads();
    const f4* tr = (const f4*)(t_items + t * CC);
    float acc = 0.0f;
    #pragma unroll
    for (int c4 = 0; c4 < 64; c4++) {
        f4 v = tr[c4];
        acc = fmaf(wl[c4*4+0], v[0], acc);
        acc = fmaf(wl[c4*4+1], v[1], acc);
        acc = fmaf(wl[c4*4+2], v[2], acc);
        acc = fmaf(wl[c4*4+3], v[3], acc);
    }
    M[o * RR + t] = acc;
}

// ---------------- k1: fused normalize -> {cue, W1@qhat} -> softmax -> y += M@attn
// LDS: qs/at share ONE 32KB buffer (qa); 33.4KB total -> 4 blocks/CU (16 waves/CU).
// R4 lesson: __launch_bounds__(256,4) alone let regalloc chase the 8-waves/EU
// bucket (<=64 VGPR) and spill ~50 regs (VGPR_Count=60, dur +15%). Pin the
// occupancy with amdgpu_waves_per_eu(4,4) => 128-VGPR budget, no spills; LDS
// caps at 4 blocks/CU regardless, so nothing is lost.
__global__ __launch_bounds__(256) __attribute__((amdgpu_waves_per_eu(4, 4)))
void k1(const float* __restrict__ query, const float* __restrict__ t_items,
        const float* __restrict__ w_out, const float* __restrict__ Mmat,
        float* __restrict__ out, float* __restrict__ gsum, float* __restrict__ gss) {
    __shared__ float qa[CC][TILE];   // 32 KB — qhat tile, then cue/attn tile
    __shared__ float red[8][TILE];
    __shared__ float pscale[TILE];
    __shared__ float smax[TILE];
    __shared__ float ssumi[TILE];

    const int t    = threadIdx.x;
    const int pix0 = blockIdx.x * TILE;
    const int b    = pix0 >> 14;
    const int hw0  = pix0 & (HWV - 1);
    const int qbase = ((b * CC) << 14) + hw0;

    // ---- Stage A: load query tile (coalesced float4), compute L2 scale, normalize in LDS
    {
        const f4* qg = (const f4*)(query + qbase);
        #pragma unroll
        for (int k = 0; k < 8; k++) {
            int f  = t + k * 256;          // float4 id: 2048 total
            int c  = f >> 3;
            int p4 = f & 7;
            f4 v = qg[c * (HWV / 4) + p4];
            *((f4*)&qa[c][p4 * 4]) = v;
        }
    }
    __syncthreads();
    {
        int p = t & 31, g = t >> 5;
        float s = 0.0f;
        #pragma unroll
        for (int cc = 0; cc < 32; cc++) { float v = qa[g * 32 + cc][p]; s = fmaf(v, v, s); }
        red[g][p] = s;
        __syncthreads();
        if (t < 32) {
            float tot = 0.0f;
            #pragma unroll
            for (int g2 = 0; g2 < 8; g2++) tot += red[g2][t];
            pscale[t] = 1.0f / fmaxf(sqrtf(tot), 1e-12f);
        }
        __syncthreads();
        #pragma unroll
        for (int k = 0; k < 8; k++) {
            int f  = t + k * 256;
            int c  = f >> 3;
            int p4 = f & 7;
            f4 v = *((f4*)&qa[c][p4 * 4]);
            v[0] *= pscale[p4 * 4 + 0];
            v[1] *= pscale[p4 * 4 + 1];
            v[2] *= pscale[p4 * 4 + 2];
            v[3] *= pscale[p4 * 4 + 3];
            *((f4*)&qa[c][p4 * 4]) = v;
        }
    }
    __syncthreads();

    const int pg = t & 7;        // pixel group
    const int p0 = pg * 4;
    const int gg = t >> 3;       // 0..31: row group (r or o)
    const int r0 = gg * 8;

    // ---- Merged stage B: cue[r][p] AND yW[o][p] in one pass over qhat
    f4 accC[8] = {f4(0.f),f4(0.f),f4(0.f),f4(0.f),f4(0.f),f4(0.f),f4(0.f),f4(0.f)};
    f4 accY[8] = {f4(0.f),f4(0.f),f4(0.f),f4(0.f),f4(0.f),f4(0.f),f4(0.f),f4(0.f)};
    {
        const float* Trow = t_items + r0 * CC;
        const float* Wrow = w_out + r0 * 512;
        for (int c4 = 0; c4 < 64; c4++) {
            int c = c4 * 4;
            f4 qv0 = *((const f4*)&qa[c + 0][p0]);
            f4 qv1 = *((const f4*)&qa[c + 1][p0]);
            f4 qv2 = *((const f4*)&qa[c + 2][p0]);
            f4 qv3 = *((const f4*)&qa[c + 3][p0]);
            #pragma unroll
            for (int i = 0; i < 8; i++) {
                f4 tv = *((const f4*)(Trow + i * CC + c));
                accC[i] += tv[0] * qv0;
                accC[i] += tv[1] * qv1;
                accC[i] += tv[2] * qv2;
                accC[i] += tv[3] * qv3;
            }
            #pragma unroll
            for (int i = 0; i < 8; i++) {
                f4 wv = *((const f4*)(Wrow + i * 512 + c));
                accY[i] += wv[0] * qv0;
                accY[i] += wv[1] * qv1;
                accY[i] += wv[2] * qv2;
                accY[i] += wv[3] * qv3;
            }
        }
    }
    __syncthreads();                       // everyone done READING qa (qhat is dead)
    #pragma unroll
    for (int i = 0; i < 8; i++) *((f4*)&qa[r0 + i][p0]) = accC[i];   // cue overwrites qa
    __syncthreads();

    // ---- Softmax over r (per pixel), normalized attn left in qa[][]
    {
        int p = t & 31, g = t >> 5;
        float m = -1e30f;
        #pragma unroll
        for (int cc = 0; cc < 32; cc++) m = fmaxf(m, qa[g * 32 + cc][p]);
        red[g][p] = m;
        __syncthreads();
        if (t < 32) {
            float mm = red[0][t];
            #pragma unroll
            for (int g2 = 1; g2 < 8; g2++) mm = fmaxf(mm, red[g2][t]);
            smax[t] = mm;
        }
        __syncthreads();
        float s = 0.0f;
        #pragma unroll
        for (int cc = 0; cc < 32; cc++) {
            float e = expf(qa[g * 32 + cc][p] - smax[p]);
            qa[g * 32 + cc][p] = e;
            s += e;
        }
        red[g][p] = s;
        __syncthreads();
        if (t < 32) {
            float tot = 0.0f;
            #pragma unroll
            for (int g2 = 0; g2 < 8; g2++) tot += red[g2][t];
            ssumi[t] = 1.0f / tot;
        }
        __syncthreads();
        #pragma unroll
        for (int k = 0; k < 8; k++) {
            int f  = t + k * 256;
            int rr = f >> 3;
            int p4 = f & 7;
            f4 v = *((f4*)&qa[rr][p4 * 4]);
            v[0] *= ssumi[p4 * 4 + 0];
            v[1] *= ssumi[p4 * 4 + 1];
            v[2] *= ssumi[p4 * 4 + 2];
            v[3] *= ssumi[p4 * 4 + 3];
            *((f4*)&qa[rr][p4 * 4]) = v;
        }
    }
    __syncthreads();

    // ---- Stage C2: accY += M @ attn, then store y + BN partial sums
    {
        const int o0 = r0;
        const float* Mrow = Mmat + o0 * RR;
        for (int r4 = 0; r4 < 64; r4++) {
            int r = r4 * 4;
            f4 av0 = *((const f4*)&qa[r + 0][p0]);
            f4 av1 = *((const f4*)&qa[r + 1][p0]);
            f4 av2 = *((const f4*)&qa[r + 2][p0]);
            f4 av3 = *((const f4*)&qa[r + 3][p0]);
            #pragma unroll
            for (int i = 0; i < 8; i++) {
                f4 mv = *((const f4*)(Mrow + i * RR + r));
                accY[i] += mv[0] * av0;
                accY[i] += mv[1] * av1;
                accY[i] += mv[2] * av2;
                accY[i] += mv[3] * av3;
            }
        }
        const int obase = ((b * COUT) << 14) + hw0;
        float psum[8], psq[8];
        #pragma unroll
        for (int i = 0; i < 8; i++) {
            f4 v = accY[i];
            *((f4*)(out + obase + (o0 + i) * HWV + p0)) = v;
            psum[i] = (v[0] + v[1]) + (v[2] + v[3]);
            psq[i]  = fmaf(v[0], v[0], fmaf(v[1], v[1], fmaf(v[2], v[2], v[3] * v[3])));
        }
        #pragma unroll
        for (int off = 1; off < 8; off <<= 1) {
            #pragma unroll
            for (int i = 0; i < 8; i++) {
                psum[i] += __shfl_xor(psum[i], off);
                psq[i]  += __shfl_xor(psq[i], off);
            }
        }
        if (pg == 0) {
            #pragma unroll
            for (int i = 0; i < 8; i++) {
                atomicAdd(&gsum[o0 + i], psum[i]);
                atomicAdd(&gss[o0 + i], psq[i]);
            }
        }
    }
}

// ---------------- k2: finalize BN affine params
__global__ void k2(const float* __restrict__ gsum, const float* __restrict__ gss,
                   const float* __restrict__ gamma, const float* __restrict__ beta,
                   float* __restrict__ params) {
    const int o = threadIdx.x;   // 256
    const float inv_n = 1.0f / (float)NPIX;
    float mean = gsum[o] * inv_n;
    float var  = gss[o] * inv_n - mean * mean;
    float sc   = gamma[o] / sqrtf(var + 1e-5f);
    params[o]        = sc;
    params[256 + o]  = beta[o] - mean * sc;
}

// ---------------- k3: apply BN + ReLU in place on d_out
__global__ void k3(float* __restrict__ out, const float* __restrict__ params) {
    const int idx = blockIdx.x * 256 + threadIdx.x;      // float4 index, total 8388608
    const int o = (idx >> 12) & 255;                     // (idx*4) >> 14
    f4* o4 = (f4*)out;
    f4 v = o4[idx];
    float sc = params[o], bi = params[256 + o];
    v[0] = fmaxf(fmaf(v[0], sc, bi), 0.0f);
    v[1] = fmaxf(fmaf(v[1], sc, bi), 0.0f);
    v[2] = fmaxf(fmaf(v[2], sc, bi), 0.0f);
    v[3] = fmaxf(fmaf(v[3], sc, bi), 0.0f);
    o4[idx] = v;
}

extern "C" void kernel_launch(void* const* d_in, const int* in_sizes, int n_in,
                              void* d_out, int out_size, void* d_ws, size_t ws_size,
                              hipStream_t stream) {
    const float* query   = (const float*)d_in[0];
    const float* t_items = (const float*)d_in[1];
    const float* w_out   = (const float*)d_in[2];
    const float* gamma   = (const float*)d_in[3];
    const float* beta    = (const float*)d_in[4];
    float* out = (float*)d_out;
    float* ws  = (float*)d_ws;

    // ws layout (floats): M[65536] | gsum[256] | gss[256] | params[512]
    float* Mmat   = ws;
    float* gsum   = ws + 65536;
    float* gss    = ws + 65536 + 256;
    float* params = ws + 65536 + 512;

    kM<<<256, 256, 0, stream>>>(w_out, t_items, Mmat, gsum, gss);
    k1<<<NPIX / TILE, 256, 0, stream>>>(query, t_items, w_out, Mmat, out, gsum, gss);
    k2<<<1, 256, 0, stream>>>(gsum, gss, gamma, beta, params);
    k3<<<NPIX * COUT / 4 / 256, 256, 0, stream>>>(out, params);
}